// Round 13
// baseline (164.716 us; speedup 1.0000x reference)
//
#include <hip/hip_runtime.h>
#include <hip/hip_fp16.h>
#include <math.h>

// SpatialSelectiveMRF: s=60000 rows, K=200 comps, dz=64, 3 spatial, n=6 neighbors.
// R13: DIAGNOSTIC — R12 numerics, but each kernel's per-tile/per-row work is
// replicated 4x inside one dispatch (opaque `zero` offset defeats CSE; writes are
// identical each rep). Both kernels become visible in top-5 with counters.
//   t_kp = dur(kp_4x)/4, t_kd = dur(kd_4x)/4.
#define KK 200
#define NT 13
#define NNB 6
#define Q8STRIDE 256
#define REPS 4

typedef __attribute__((ext_vector_type(8))) short short8;
typedef __attribute__((ext_vector_type(4))) float f32x4;
typedef _Float16 half2v __attribute__((ext_vector_type(2)));
typedef __fp16 fp16x2 __attribute__((ext_vector_type(2)));
#define MFMA16 __builtin_amdgcn_mfma_f32_16x16x32_bf16

union U8 { short8 s; uint4 u; };
union H2U { half2v h; unsigned u; };
union P2U { fp16x2 h; unsigned u; };

__device__ __forceinline__ unsigned short bfh(float f) {
    unsigned u = __float_as_uint(f);
    return (unsigned short)((u + 0x7fffu + ((u >> 16) & 1u)) >> 16);  // RNE
}
__device__ __forceinline__ float bf2f(unsigned short h) {
    return __uint_as_float(((unsigned)h) << 16);
}
__device__ __forceinline__ short8 z8() {
    short8 v;
#pragma unroll
    for (int j = 0; j < 8; ++j) v[j] = 0;
    return v;
}
// trunc hi/lo split of a float PAIR -> packed bf16 words, IN ORDER.
__device__ __forceinline__ void cvp(float f0, float f1, unsigned& hw, unsigned& lw) {
    unsigned u0 = __float_as_uint(f0), u1 = __float_as_uint(f1);
    float l0 = f0 - __uint_as_float(u0 & 0xffff0000u);
    float l1 = f1 - __uint_as_float(u1 & 0xffff0000u);
    hw = __builtin_amdgcn_perm(u1, u0, 0x07060302u);  // {f0.hi16 | f1.hi16<<16}
    lw = __builtin_amdgcn_perm(__float_as_uint(l1), __float_as_uint(l0), 0x07060302u);
}
__device__ __forceinline__ unsigned e5pair_lo(unsigned w) {
    return __builtin_amdgcn_perm(w, 0u, 0x05000400u);
}
__device__ __forceinline__ unsigned e5pair_hi(unsigned w) {
    return __builtin_amdgcn_perm(w, 0u, 0x07000600u);
}
__device__ __forceinline__ half2v as_h2(unsigned u) { H2U x; x.u = u; return x.h; }
__device__ __forceinline__ unsigned pkrtz_u(float a, float b) {
    P2U x; x.h = __builtin_amdgcn_cvt_pkrtz(a, b); return x.u;
}

__global__ __launch_bounds__(512, 4) void
k_point(const float* __restrict__ Z, const float* __restrict__ S,
        const float* __restrict__ selmu, const float* __restrict__ spamu,
        unsigned char* __restrict__ Qc8, float* __restrict__ pointbuf,
        int sRows, int mTiles, int zero)
{
    __shared__ short8 ldsBh[26 * 64];
    __shared__ short8 ldsBl[26 * 64];
    __shared__ uint2  ldsB2h[NT * 16];
    __shared__ uint2  ldsB2l[NT * 16];
    __shared__ float  normAcc[NT * 16];

    const int tid = threadIdx.x;

    if (tid < NT * 16) normAcc[tid] = 0.f;
    __syncthreads();

    // ---- staging (ONCE; barriers all live here) ----
    for (int slot = tid; slot < 26 * 64; slot += 512) {
        int L = slot & 63, ts = slot >> 6;
        int t = ts >> 1, sstep = ts & 1;
        int n = t * 16 + (L & 15);
        int kb = sstep * 32 + (L >> 4) * 8;
        U8 hi, lo;
        hi.s = z8(); lo.s = z8();
        if (n < KK) {
            const float* mp = selmu + (size_t)n * 64 + kb;
            float4 a = *(const float4*)mp;
            float4 b = *(const float4*)(mp + 4);
            cvp(a.x, a.y, hi.u.x, lo.u.x);
            cvp(a.z, a.w, hi.u.y, lo.u.y);
            cvp(b.x, b.y, hi.u.z, lo.u.z);
            cvp(b.z, b.w, hi.u.w, lo.u.w);
            float ss = a.x*a.x + a.y*a.y + a.z*a.z + a.w*a.w
                     + b.x*b.x + b.y*b.y + b.z*b.z + b.w*b.w;
            atomicAdd(&normAcc[n], ss);
        }
        ldsBh[slot] = hi.s;
        ldsBl[slot] = lo.s;
    }
    __syncthreads();
    if (tid < NT * 16) {
        int n = tid;
        uint2 vh = make_uint2(0, 0), vl = make_uint2(0, 0);
        if (n < KK) {
            float p0 = spamu[n * 3 + 0], p1 = spamu[n * 3 + 1], p2 = spamu[n * 3 + 2];
            float nrm = -0.5f * (normAcc[n] + p0 * p0 + p1 * p1 + p2 * p2);
            unsigned short h0 = bfh(p0), h1 = bfh(p1), h2 = bfh(p2), h3 = bfh(nrm);
            unsigned short g0 = bfh(p0 - bf2f(h0)), g1 = bfh(p1 - bf2f(h1));
            unsigned short g2 = bfh(p2 - bf2f(h2)), g3 = bfh(nrm - bf2f(h3));
            vh = make_uint2((unsigned)h0 | ((unsigned)h1 << 16), (unsigned)h2 | ((unsigned)h3 << 16));
            vl = make_uint2((unsigned)g0 | ((unsigned)g1 << 16), (unsigned)g2 | ((unsigned)g3 << 16));
        }
        ldsB2h[tid] = vh;
        ldsB2l[tid] = vl;
    }
    __syncthreads();   // last barrier; rep loop below is barrier-free

    const int wave = tid >> 6;
    const int lane = tid & 63;
    const int q = lane >> 4;
    const int li = lane & 15;
    const float cLog = 0.5f * 67.0f * 1.8378770664093453f;

    const int tile = blockIdx.x * 8 + wave;
    const int m0 = tile * 16;
    const int row = m0 + li;
    const int rowA = (row < sRows) ? row : (sRows - 1);

    for (int rep = 0; rep < REPS; ++rep) {
        if (tile >= mTiles) continue;
        // opaque per-rep offsets (zero == 0 at runtime) defeat cross-rep CSE
        const float* Zr = Z + (size_t)zero * rep;
        const float* Sr = S + (size_t)zero * rep;
        unsigned char* Q8r = Qc8 + (size_t)zero * rep;
        float* pbr = pointbuf + (size_t)zero * rep;

        const float* zr = Zr + (size_t)rowA * 64 + q * 8;
        float4 z0 = *(const float4*)zr;
        float4 z1 = *(const float4*)(zr + 4);
        float4 z2 = *(const float4*)(zr + 32);
        float4 z3 = *(const float4*)(zr + 36);
        U8 ah0, al0, ah1, al1;
        cvp(z0.x, z0.y, ah0.u.x, al0.u.x);
        cvp(z0.z, z0.w, ah0.u.y, al0.u.y);
        cvp(z1.x, z1.y, ah0.u.z, al0.u.z);
        cvp(z1.z, z1.w, ah0.u.w, al0.u.w);
        cvp(z2.x, z2.y, ah1.u.x, al1.u.x);
        cvp(z2.z, z2.w, ah1.u.y, al1.u.y);
        cvp(z3.x, z3.y, ah1.u.z, al1.u.z);
        cvp(z3.z, z3.w, ah1.u.w, al1.u.w);

        float zz = z0.x*z0.x + z0.y*z0.y + z0.z*z0.z + z0.w*z0.w
                 + z1.x*z1.x + z1.y*z1.y + z1.z*z1.z + z1.w*z1.w
                 + z2.x*z2.x + z2.y*z2.y + z2.z*z2.z + z2.w*z2.w
                 + z3.x*z3.x + z3.y*z3.y + z3.z*z3.z + z3.w*z3.w;
        zz += __shfl_xor(zz, 16);
        zz += __shfl_xor(zz, 32);

        float s0v = Sr[(size_t)rowA * 3 + 0];
        float s1v = Sr[(size_t)rowA * 3 + 1];
        float s2v = Sr[(size_t)rowA * 3 + 2];
        float cz = 0.5f * (zz + s0v * s0v + s1v * s1v + s2v * s2v) + cLog;

        U8 rsh, rsl;
        rsh.s = z8(); rsl.s = z8();
        if (lane < 16) {
            cvp(s0v, s1v, rsh.u.x, rsl.u.x);
            unsigned hw, lw;
            cvp(s2v, 1.0f, hw, lw);
            rsh.u.y = hw;
            rsl.u.y = lw & 0x0000ffffu;
        }

        f32x4 acc[NT];
#pragma unroll
        for (int t = 0; t < NT; ++t) { f32x4 zv = {0.f, 0.f, 0.f, 0.f}; acc[t] = zv; }

#pragma unroll
        for (int t = 0; t < NT; ++t) {
            short8 b0 = ldsBh[(t * 2 + 0) * 64 + lane];
            short8 b1 = ldsBh[(t * 2 + 1) * 64 + lane];
            short8 c0 = ldsBl[(t * 2 + 0) * 64 + lane];
            short8 c1 = ldsBl[(t * 2 + 1) * 64 + lane];
            uint2 bh2 = make_uint2(0, 0), bl2 = make_uint2(0, 0);
            if (lane < 16) { bh2 = ldsB2h[t * 16 + lane]; bl2 = ldsB2l[t * 16 + lane]; }
            U8 cmh, cml;
            cmh.s = z8(); cml.s = z8();
            cmh.u.x = bh2.x; cmh.u.y = bh2.y;
            cml.u.x = bl2.x; cml.u.y = bl2.y;

            acc[t] = MFMA16(b0, ah0.s, acc[t], 0, 0, 0);
            acc[t] = MFMA16(b1, ah1.s, acc[t], 0, 0, 0);
            acc[t] = MFMA16(b0, al0.s, acc[t], 0, 0, 0);
            acc[t] = MFMA16(b1, al1.s, acc[t], 0, 0, 0);
            acc[t] = MFMA16(c0, ah0.s, acc[t], 0, 0, 0);
            acc[t] = MFMA16(c1, ah1.s, acc[t], 0, 0, 0);
            acc[t] = MFMA16(cmh.s, rsh.s, acc[t], 0, 0, 0);
            acc[t] = MFMA16(cmh.s, rsl.s, acc[t], 0, 0, 0);
            acc[t] = MFMA16(cml.s, rsh.s, acc[t], 0, 0, 0);
        }

        const bool padQ = (q >= 2);
        float mx = -1e30f;
#pragma unroll
        for (int t = 0; t < NT; ++t) {
#pragma unroll
            for (int r = 0; r < 4; ++r) {
                float v = acc[t][r];
                if (t == 12 && padQ) v = -1e30f;
                acc[t][r] = v;
                mx = fmaxf(mx, v);
            }
        }
        mx = fmaxf(mx, __shfl_xor(mx, 16));
        mx = fmaxf(mx, __shfl_xor(mx, 32));
        float sl = 0.f, pl = 0.f;
#pragma unroll
        for (int t = 0; t < NT; ++t) {
#pragma unroll
            for (int r = 0; r < 4; ++r) {
                float v = acc[t][r];
                float ee = __expf(v - mx);
                sl += ee;
                pl = fmaf(ee, v, pl);
                acc[t][r] = ee;
            }
        }
        sl += __shfl_xor(sl, 16);
        sl += __shfl_xor(sl, 32);
        pl += __shfl_xor(pl, 16);
        pl += __shfl_xor(pl, 32);
        float inv = 1.0f / sl;

        if (row < sRows) {
            unsigned char* qp = Q8r + (size_t)row * Q8STRIDE + q * 4;
#pragma unroll
            for (int t = 0; t < NT; ++t) {
                unsigned w = 0;
                if (t < 12 || !padQ) {
                    float c0 = fminf(fmaxf(acc[t][0] * inv, 1e-6f), 1.0f - 1e-6f) * 1024.0f;
                    float c1 = fminf(fmaxf(acc[t][1] * inv, 1e-6f), 1.0f - 1e-6f) * 1024.0f;
                    float c2 = fminf(fmaxf(acc[t][2] * inv, 1e-6f), 1.0f - 1e-6f) * 1024.0f;
                    float c3 = fminf(fmaxf(acc[t][3] * inv, 1e-6f), 1.0f - 1e-6f) * 1024.0f;
                    unsigned ua = pkrtz_u(c0, c1);
                    unsigned ub = pkrtz_u(c2, c3);
                    unsigned t0 = ua + 0x007f007fu + ((ua >> 8) & 0x00010001u);
                    unsigned t1 = ub + 0x007f007fu + ((ub >> 8) & 0x00010001u);
                    w = __builtin_amdgcn_perm(t1, t0, 0x07050301u);
                }
                *(unsigned*)(qp + t * 16) = w;
            }
            if (lane < 16) pbr[row] = cz - pl * inv;
        }
    }
}

__global__ __launch_bounds__(512, 8) void
k_doublet(const unsigned char* __restrict__ Qc8, const float* __restrict__ pointbuf,
          const int* __restrict__ D, float* __restrict__ out, int sRows, int zero)
{
    const int wave = threadIdx.x >> 6;
    const int lane = threadIdx.x & 63;
    const int half = lane >> 5;
    const int l = lane & 31;
    const int row = blockIdx.x * 8 + wave;
    if (row >= sRows) return;

    const bool act = (l < 25);
    const int lc = act ? l : 0;
    const float LN2_20 = 13.862943611198906f;

    for (int rep = 0; rep < REPS; ++rep) {
        const unsigned char* Q8r = Qc8 + (size_t)zero * rep;
        const int* Dr = D + (size_t)zero * rep;
        const float* pbr = pointbuf + (size_t)zero * rep;
        float* outr = out + (size_t)zero * rep;

        const int* dp = Dr + (size_t)row * NNB;
        int da0 = dp[0], da1 = dp[1], da2 = dp[2], da3 = dp[3], da4 = dp[4], da5 = dp[5];
        int dj[3];
        dj[0] = half ? da1 : da0;
        dj[1] = half ? da3 : da2;
        dj[2] = half ? da5 : da4;

        uint2 ow = *(const uint2*)(Q8r + (size_t)row * Q8STRIDE + lc * 8);
        uint2 nb[3];
#pragma unroll
        for (int i = 0; i < 3; ++i) {
            int dd = (dj[i] >= 0) ? dj[i] : row;
            nb[i] = *(const uint2*)(Q8r + (size_t)dd * Q8STRIDE + lc * 8);
        }

        unsigned o0 = e5pair_lo(ow.x), o1 = e5pair_hi(ow.x);
        unsigned o2 = e5pair_lo(ow.y), o3 = e5pair_hi(ow.y);

        float pj[3];
#pragma unroll
        for (int i = 0; i < 3; ++i) {
            unsigned b0 = e5pair_lo(nb[i].x), b1 = e5pair_hi(nb[i].x);
            unsigned b2 = e5pair_lo(nb[i].y), b3 = e5pair_hi(nb[i].y);
            float t = 0.f;
#if __has_builtin(__builtin_amdgcn_fdot2)
            t = __builtin_amdgcn_fdot2(as_h2(o0), as_h2(b0), t, false);
            t = __builtin_amdgcn_fdot2(as_h2(o1), as_h2(b1), t, false);
            t = __builtin_amdgcn_fdot2(as_h2(o2), as_h2(b2), t, false);
            t = __builtin_amdgcn_fdot2(as_h2(o3), as_h2(b3), t, false);
#else
            {
                half2v ov[4] = { as_h2(o0), as_h2(o1), as_h2(o2), as_h2(o3) };
                half2v bv[4] = { as_h2(b0), as_h2(b1), as_h2(b2), as_h2(b3) };
#pragma unroll
                for (int k = 0; k < 4; ++k) {
                    t = fmaf((float)ov[k][0], (float)bv[k][0], t);
                    t = fmaf((float)ov[k][1], (float)bv[k][1], t);
                }
            }
#endif
            pj[i] = act ? t : 0.f;
        }
#pragma unroll
        for (int off = 1; off <= 16; off <<= 1) {
#pragma unroll
            for (int i = 0; i < 3; ++i) pj[i] += __shfl_xor(pj[i], off);
        }
        float dbl = 0.f;
#pragma unroll
        for (int i = 0; i < 3; ++i)
            if (dj[i] >= 0) dbl += LN2_20 - __logf(pj[i]);
        dbl += __shfl_xor(dbl, 32);

        if (lane == 0) outr[row] = pbr[row] + dbl;
    }
}

extern "C" void kernel_launch(void* const* d_in, const int* in_sizes, int n_in,
                              void* d_out, int out_size, void* d_ws, size_t ws_size,
                              hipStream_t stream) {
    const float* Z     = (const float*)d_in[0];
    const float* S     = (const float*)d_in[1];
    const int*   D     = (const int*)d_in[2];
    const float* selmu = (const float*)d_in[3];
    const float* spamu = (const float*)d_in[4];
    float* out = (float*)d_out;
    const int s = out_size;                    // 60000
    const int zero = 0;                        // opaque to device code

    unsigned char* Qc8 = (unsigned char*)d_ws;                   // s*256 B = 15.36 MB
    float* pointbuf = (float*)((char*)d_ws + (size_t)s * Q8STRIDE);

    const int mTiles = (s + 15) / 16;          // 3750
    const int grid1 = (mTiles + 7) / 8;        // 469
    k_point<<<grid1, 512, 0, stream>>>(Z, S, selmu, spamu, Qc8, pointbuf, s, mTiles, zero);

    const int grid2 = (s + 7) / 8;             // 7500: one row per wave
    k_doublet<<<grid2, 512, 0, stream>>>(Qc8, pointbuf, D, out, s, zero);
}

// Round 14
// 101.577 us; speedup vs baseline: 1.6216x; 1.6216x over previous
//
#include <hip/hip_runtime.h>
#include <hip/hip_fp16.h>
#include <math.h>

// SpatialSelectiveMRF: s=60000 rows, K=200 comps, dz=64, 3 spatial, n=6 neighbors.
// R14: kd restructured — 16 lanes/row (4 rows/wave), uint4 loads cover the full
// 256-comp padded row, reduction = 4 DPP row_ror adds (no ds_swizzle butterfly).
// kp: R12 numerics + zero-fill of pad bytes 208..255 (kd now reads them).
#define KK 200
#define NT 13
#define NNB 6
#define Q8STRIDE 256

typedef __attribute__((ext_vector_type(8))) short short8;
typedef __attribute__((ext_vector_type(4))) float f32x4;
typedef _Float16 half2v __attribute__((ext_vector_type(2)));
typedef __fp16 fp16x2 __attribute__((ext_vector_type(2)));
#define MFMA16 __builtin_amdgcn_mfma_f32_16x16x32_bf16

union U8 { short8 s; uint4 u; };
union H2U { half2v h; unsigned u; };
union P2U { fp16x2 h; unsigned u; };

__device__ __forceinline__ unsigned short bfh(float f) {
    unsigned u = __float_as_uint(f);
    return (unsigned short)((u + 0x7fffu + ((u >> 16) & 1u)) >> 16);  // RNE
}
__device__ __forceinline__ float bf2f(unsigned short h) {
    return __uint_as_float(((unsigned)h) << 16);
}
__device__ __forceinline__ short8 z8() {
    short8 v;
#pragma unroll
    for (int j = 0; j < 8; ++j) v[j] = 0;
    return v;
}
// trunc hi/lo split of a float PAIR -> packed bf16 words, IN ORDER.
__device__ __forceinline__ void cvp(float f0, float f1, unsigned& hw, unsigned& lw) {
    unsigned u0 = __float_as_uint(f0), u1 = __float_as_uint(f1);
    float l0 = f0 - __uint_as_float(u0 & 0xffff0000u);
    float l1 = f1 - __uint_as_float(u1 & 0xffff0000u);
    hw = __builtin_amdgcn_perm(u1, u0, 0x07060302u);  // {f0.hi16 | f1.hi16<<16}
    lw = __builtin_amdgcn_perm(__float_as_uint(l1), __float_as_uint(l0), 0x07060302u);
}
__device__ __forceinline__ unsigned e5pair_lo(unsigned w) {
    return __builtin_amdgcn_perm(w, 0u, 0x05000400u);   // bytes 0,1 -> f16 pair
}
__device__ __forceinline__ unsigned e5pair_hi(unsigned w) {
    return __builtin_amdgcn_perm(w, 0u, 0x07000600u);   // bytes 2,3 -> f16 pair
}
__device__ __forceinline__ half2v as_h2(unsigned u) { H2U x; x.u = u; return x.h; }
__device__ __forceinline__ unsigned pkrtz_u(float a, float b) {
    P2U x; x.h = __builtin_amdgcn_cvt_pkrtz(a, b); return x.u;
}
// add value rotated within the 16-lane DPP row (row_ror:n -> ctrl 0x120+n)
#define DPP_ROR_ADD(t, ctrl)                                                        \
    t += __int_as_float(__builtin_amdgcn_update_dpp(0, __float_as_int(t), (ctrl),   \
                                                    0xF, 0xF, true))

// MFMA 16x16x32 layouts: A: lane holds A[m=lane&15][k=(lane>>4)*8+j];
// B: lane holds B[k=(lane>>4)*8+j][n=lane&15]; D: [row=(lane>>4)*4+r][col=lane&15].
__global__ __launch_bounds__(512, 4) void
k_point(const float* __restrict__ Z, const float* __restrict__ S,
        const float* __restrict__ selmu, const float* __restrict__ spamu,
        unsigned char* __restrict__ Qc8, float* __restrict__ pointbuf,
        int sRows, int mTiles)
{
    __shared__ short8 ldsBh[26 * 64];
    __shared__ short8 ldsBl[26 * 64];
    __shared__ uint2  ldsB2h[NT * 16];
    __shared__ uint2  ldsB2l[NT * 16];
    __shared__ float  normAcc[NT * 16];

    const int tid = threadIdx.x;

    if (tid < NT * 16) normAcc[tid] = 0.f;
    __syncthreads();

    for (int slot = tid; slot < 26 * 64; slot += 512) {
        int L = slot & 63, ts = slot >> 6;
        int t = ts >> 1, sstep = ts & 1;
        int n = t * 16 + (L & 15);
        int kb = sstep * 32 + (L >> 4) * 8;
        U8 hi, lo;
        hi.s = z8(); lo.s = z8();
        if (n < KK) {
            const float* mp = selmu + (size_t)n * 64 + kb;
            float4 a = *(const float4*)mp;
            float4 b = *(const float4*)(mp + 4);
            cvp(a.x, a.y, hi.u.x, lo.u.x);
            cvp(a.z, a.w, hi.u.y, lo.u.y);
            cvp(b.x, b.y, hi.u.z, lo.u.z);
            cvp(b.z, b.w, hi.u.w, lo.u.w);
            float ss = a.x*a.x + a.y*a.y + a.z*a.z + a.w*a.w
                     + b.x*b.x + b.y*b.y + b.z*b.z + b.w*b.w;
            atomicAdd(&normAcc[n], ss);
        }
        ldsBh[slot] = hi.s;
        ldsBl[slot] = lo.s;
    }
    __syncthreads();
    if (tid < NT * 16) {
        int n = tid;
        uint2 vh = make_uint2(0, 0), vl = make_uint2(0, 0);
        if (n < KK) {
            float p0 = spamu[n * 3 + 0], p1 = spamu[n * 3 + 1], p2 = spamu[n * 3 + 2];
            float nrm = -0.5f * (normAcc[n] + p0 * p0 + p1 * p1 + p2 * p2);
            unsigned short h0 = bfh(p0), h1 = bfh(p1), h2 = bfh(p2), h3 = bfh(nrm);
            unsigned short g0 = bfh(p0 - bf2f(h0)), g1 = bfh(p1 - bf2f(h1));
            unsigned short g2 = bfh(p2 - bf2f(h2)), g3 = bfh(nrm - bf2f(h3));
            vh = make_uint2((unsigned)h0 | ((unsigned)h1 << 16), (unsigned)h2 | ((unsigned)h3 << 16));
            vl = make_uint2((unsigned)g0 | ((unsigned)g1 << 16), (unsigned)g2 | ((unsigned)g3 << 16));
        }
        ldsB2h[tid] = vh;
        ldsB2l[tid] = vl;
    }
    __syncthreads();

    const int wave = tid >> 6;
    const int lane = tid & 63;
    const int q = lane >> 4;
    const int li = lane & 15;
    const float cLog = 0.5f * 67.0f * 1.8378770664093453f;

    const int tile = blockIdx.x * 8 + wave;
    if (tile >= mTiles) return;
    const int m0 = tile * 16;
    const int row = m0 + li;
    const int rowA = (row < sRows) ? row : (sRows - 1);

    const float* zr = Z + (size_t)rowA * 64 + q * 8;
    float4 z0 = *(const float4*)zr;
    float4 z1 = *(const float4*)(zr + 4);
    float4 z2 = *(const float4*)(zr + 32);
    float4 z3 = *(const float4*)(zr + 36);
    U8 ah0, al0, ah1, al1;
    cvp(z0.x, z0.y, ah0.u.x, al0.u.x);
    cvp(z0.z, z0.w, ah0.u.y, al0.u.y);
    cvp(z1.x, z1.y, ah0.u.z, al0.u.z);
    cvp(z1.z, z1.w, ah0.u.w, al0.u.w);
    cvp(z2.x, z2.y, ah1.u.x, al1.u.x);
    cvp(z2.z, z2.w, ah1.u.y, al1.u.y);
    cvp(z3.x, z3.y, ah1.u.z, al1.u.z);
    cvp(z3.z, z3.w, ah1.u.w, al1.u.w);

    float zz = z0.x*z0.x + z0.y*z0.y + z0.z*z0.z + z0.w*z0.w
             + z1.x*z1.x + z1.y*z1.y + z1.z*z1.z + z1.w*z1.w
             + z2.x*z2.x + z2.y*z2.y + z2.z*z2.z + z2.w*z2.w
             + z3.x*z3.x + z3.y*z3.y + z3.z*z3.z + z3.w*z3.w;
    zz += __shfl_xor(zz, 16);
    zz += __shfl_xor(zz, 32);

    float s0v = S[(size_t)rowA * 3 + 0];
    float s1v = S[(size_t)rowA * 3 + 1];
    float s2v = S[(size_t)rowA * 3 + 2];
    float cz = 0.5f * (zz + s0v * s0v + s1v * s1v + s2v * s2v) + cLog;

    U8 rsh, rsl;
    rsh.s = z8(); rsl.s = z8();
    if (lane < 16) {
        cvp(s0v, s1v, rsh.u.x, rsl.u.x);
        unsigned hw, lw;
        cvp(s2v, 1.0f, hw, lw);
        rsh.u.y = hw;
        rsl.u.y = lw & 0x0000ffffu;
    }

    f32x4 acc[NT];
#pragma unroll
    for (int t = 0; t < NT; ++t) { f32x4 zv = {0.f, 0.f, 0.f, 0.f}; acc[t] = zv; }

#pragma unroll
    for (int t = 0; t < NT; ++t) {
        short8 b0 = ldsBh[(t * 2 + 0) * 64 + lane];
        short8 b1 = ldsBh[(t * 2 + 1) * 64 + lane];
        short8 c0 = ldsBl[(t * 2 + 0) * 64 + lane];
        short8 c1 = ldsBl[(t * 2 + 1) * 64 + lane];
        uint2 bh2 = make_uint2(0, 0), bl2 = make_uint2(0, 0);
        if (lane < 16) { bh2 = ldsB2h[t * 16 + lane]; bl2 = ldsB2l[t * 16 + lane]; }
        U8 cmh, cml;
        cmh.s = z8(); cml.s = z8();
        cmh.u.x = bh2.x; cmh.u.y = bh2.y;
        cml.u.x = bl2.x; cml.u.y = bl2.y;

        acc[t] = MFMA16(b0, ah0.s, acc[t], 0, 0, 0);
        acc[t] = MFMA16(b1, ah1.s, acc[t], 0, 0, 0);
        acc[t] = MFMA16(b0, al0.s, acc[t], 0, 0, 0);
        acc[t] = MFMA16(b1, al1.s, acc[t], 0, 0, 0);
        acc[t] = MFMA16(c0, ah0.s, acc[t], 0, 0, 0);
        acc[t] = MFMA16(c1, ah1.s, acc[t], 0, 0, 0);
        acc[t] = MFMA16(cmh.s, rsh.s, acc[t], 0, 0, 0);
        acc[t] = MFMA16(cmh.s, rsl.s, acc[t], 0, 0, 0);
        acc[t] = MFMA16(cml.s, rsh.s, acc[t], 0, 0, 0);
    }

    const bool padQ = (q >= 2);
    float mx = -1e30f;
#pragma unroll
    for (int t = 0; t < NT; ++t) {
#pragma unroll
        for (int r = 0; r < 4; ++r) {
            float v = acc[t][r];
            if (t == 12 && padQ) v = -1e30f;
            acc[t][r] = v;
            mx = fmaxf(mx, v);
        }
    }
    mx = fmaxf(mx, __shfl_xor(mx, 16));
    mx = fmaxf(mx, __shfl_xor(mx, 32));
    float sl = 0.f, pl = 0.f;
#pragma unroll
    for (int t = 0; t < NT; ++t) {
#pragma unroll
        for (int r = 0; r < 4; ++r) {
            float v = acc[t][r];
            float ee = __expf(v - mx);
            sl += ee;
            pl = fmaf(ee, v, pl);
            acc[t][r] = ee;
        }
    }
    sl += __shfl_xor(sl, 16);
    sl += __shfl_xor(sl, 32);
    pl += __shfl_xor(pl, 16);
    pl += __shfl_xor(pl, 32);
    float inv = 1.0f / sl;

    if (row < sRows) {
        unsigned char* qp = Qc8 + (size_t)row * Q8STRIDE + q * 4;
#pragma unroll
        for (int t = 0; t < NT; ++t) {
            unsigned w = 0;
            if (t < 12 || !padQ) {
                float c0 = fminf(fmaxf(acc[t][0] * inv, 1e-6f), 1.0f - 1e-6f) * 1024.0f;
                float c1 = fminf(fmaxf(acc[t][1] * inv, 1e-6f), 1.0f - 1e-6f) * 1024.0f;
                float c2 = fminf(fmaxf(acc[t][2] * inv, 1e-6f), 1.0f - 1e-6f) * 1024.0f;
                float c3 = fminf(fmaxf(acc[t][3] * inv, 1e-6f), 1.0f - 1e-6f) * 1024.0f;
                unsigned ua = pkrtz_u(c0, c1);
                unsigned ub = pkrtz_u(c2, c3);
                unsigned t0 = ua + 0x007f007fu + ((ua >> 8) & 0x00010001u);
                unsigned t1 = ub + 0x007f007fu + ((ub >> 8) & 0x00010001u);
                w = __builtin_amdgcn_perm(t1, t0, 0x07050301u);
            }
            *(unsigned*)(qp + t * 16) = w;
        }
        // zero-fill pad comps 208..255 (kd reads the full 256B row)
        *(unsigned*)(qp + 13 * 16) = 0u;
        *(unsigned*)(qp + 14 * 16) = 0u;
        *(unsigned*)(qp + 15 * 16) = 0u;
        if (lane < 16) pointbuf[row] = cz - pl * inv;
    }
}

// k_doublet R14: 16 lanes per row, 4 rows per wave. Lane l16 owns comps
// [l16*16, l16*16+16) via one uint4; all decode/dot/reduce wave-instructions
// process 4 rows simultaneously. Reduction: 4 DPP row_ror adds (16-lane row).
__global__ __launch_bounds__(512, 8) void
k_doublet(const unsigned char* __restrict__ Qc8, const float* __restrict__ pointbuf,
          const int* __restrict__ D, float* __restrict__ out, int sRows)
{
    const int lane = threadIdx.x & 63;
    const int wave = threadIdx.x >> 6;
    const int g = lane >> 4;        // row group within wave
    const int l16 = lane & 15;
    const int row = blockIdx.x * 32 + wave * 4 + g;
    if (row >= sRows) return;

    const float LN2_20 = 13.862943611198906f;   // own,nb both x1024 -> co x 2^20

    // 6 neighbor ids (same within 16-lane group; per-lane loads hit L1)
    const int* dp = D + (size_t)row * NNB;
    int2 d01 = *(const int2*)dp;
    int2 d23 = *(const int2*)(dp + 2);
    int2 d45 = *(const int2*)(dp + 4);
    const int dj[6] = { d01.x, d01.y, d23.x, d23.y, d45.x, d45.y };

    const unsigned off = (unsigned)l16 * 16u;
    uint4 ow = *(const uint4*)(Qc8 + (size_t)row * Q8STRIDE + off);
    uint4 nb[NNB];
#pragma unroll
    for (int j = 0; j < NNB; ++j) {
        int dd = (dj[j] >= 0) ? dj[j] : row;
        nb[j] = *(const uint4*)(Qc8 + (size_t)dd * Q8STRIDE + off);
    }

    unsigned o0 = e5pair_lo(ow.x), o1 = e5pair_hi(ow.x);
    unsigned o2 = e5pair_lo(ow.y), o3 = e5pair_hi(ow.y);
    unsigned o4 = e5pair_lo(ow.z), o5 = e5pair_hi(ow.z);
    unsigned o6 = e5pair_lo(ow.w), o7 = e5pair_hi(ow.w);

    float dbl = 0.f;
#pragma unroll
    for (int j = 0; j < NNB; ++j) {
        float t = 0.f;
#if __has_builtin(__builtin_amdgcn_fdot2)
        t = __builtin_amdgcn_fdot2(as_h2(o0), as_h2(e5pair_lo(nb[j].x)), t, false);
        t = __builtin_amdgcn_fdot2(as_h2(o1), as_h2(e5pair_hi(nb[j].x)), t, false);
        t = __builtin_amdgcn_fdot2(as_h2(o2), as_h2(e5pair_lo(nb[j].y)), t, false);
        t = __builtin_amdgcn_fdot2(as_h2(o3), as_h2(e5pair_hi(nb[j].y)), t, false);
        t = __builtin_amdgcn_fdot2(as_h2(o4), as_h2(e5pair_lo(nb[j].z)), t, false);
        t = __builtin_amdgcn_fdot2(as_h2(o5), as_h2(e5pair_hi(nb[j].z)), t, false);
        t = __builtin_amdgcn_fdot2(as_h2(o6), as_h2(e5pair_lo(nb[j].w)), t, false);
        t = __builtin_amdgcn_fdot2(as_h2(o7), as_h2(e5pair_hi(nb[j].w)), t, false);
#else
        {
            unsigned ov[8] = { o0, o1, o2, o3, o4, o5, o6, o7 };
            unsigned bv[8] = { e5pair_lo(nb[j].x), e5pair_hi(nb[j].x),
                               e5pair_lo(nb[j].y), e5pair_hi(nb[j].y),
                               e5pair_lo(nb[j].z), e5pair_hi(nb[j].z),
                               e5pair_lo(nb[j].w), e5pair_hi(nb[j].w) };
#pragma unroll
            for (int k = 0; k < 8; ++k) {
                half2v a = as_h2(ov[k]), b = as_h2(bv[k]);
                t = fmaf((float)a[0], (float)b[0], t);
                t = fmaf((float)a[1], (float)b[1], t);
            }
        }
#endif
        // sum over the 16-lane group: rotate-add within DPP row
        DPP_ROR_ADD(t, 0x128);   // row_ror:8
        DPP_ROR_ADD(t, 0x124);   // row_ror:4
        DPP_ROR_ADD(t, 0x122);   // row_ror:2
        DPP_ROR_ADD(t, 0x121);   // row_ror:1
        if (dj[j] >= 0) dbl += LN2_20 - __logf(t);
    }

    if (l16 == 0) out[row] = pointbuf[row] + dbl;
}

extern "C" void kernel_launch(void* const* d_in, const int* in_sizes, int n_in,
                              void* d_out, int out_size, void* d_ws, size_t ws_size,
                              hipStream_t stream) {
    const float* Z     = (const float*)d_in[0];
    const float* S     = (const float*)d_in[1];
    const int*   D     = (const int*)d_in[2];
    const float* selmu = (const float*)d_in[3];
    const float* spamu = (const float*)d_in[4];
    float* out = (float*)d_out;
    const int s = out_size;                    // 60000

    unsigned char* Qc8 = (unsigned char*)d_ws;                   // s*256 B = 15.36 MB
    float* pointbuf = (float*)((char*)d_ws + (size_t)s * Q8STRIDE);

    const int mTiles = (s + 15) / 16;          // 3750
    const int grid1 = (mTiles + 7) / 8;        // 469
    k_point<<<grid1, 512, 0, stream>>>(Z, S, selmu, spamu, Qc8, pointbuf, s, mTiles);

    const int grid2 = (s + 31) / 32;           // 1875: 4 rows/wave, 8 waves/block
    k_doublet<<<grid2, 512, 0, stream>>>(Qc8, pointbuf, D, out, s);
}